// Round 10
// baseline (93.022 us; speedup 1.0000x reference)
//
#include <hip/hip_runtime.h>

typedef __attribute__((ext_vector_type(8))) short short8v;
typedef __attribute__((ext_vector_type(4))) float float4v;
typedef unsigned int uint;

#define TWO_LOG2E 2.8853900817779268f   // 2*log2(e)
#define LOG2E     1.4426950408889634f

// ---------------------------------------------------------------------------
// f32 -> bf16 helpers
// ---------------------------------------------------------------------------
__device__ inline uint rne_bf16(float x) {
    uint u = __float_as_uint(x);
    return (u + 0x7fffu + ((u >> 16) & 1u)) >> 16;
}
__device__ inline uint pack_hi_lo(float a0, float a1, uint& lo_pack) {
    const uint h0 = rne_bf16(a0), h1 = rne_bf16(a1);
    const float f0 = __uint_as_float(h0 << 16), f1 = __uint_as_float(h1 << 16);
    const float l0 = a0 - f0, l1 = a1 - f1;
    lo_pack = (rne_bf16(l1) << 16) | rne_bf16(l0);
    return (h1 << 16) | h0;
}
// trunc-hi split of 8 f32 into bf16 hi/lo fragments (cheap in-kernel path)
__device__ inline void split8(const float4 x0, const float4 x1,
                              short8v& h, short8v& l) {
    const float xs[8] = {x0.x, x0.y, x0.z, x0.w, x1.x, x1.y, x1.z, x1.w};
    #pragma unroll
    for (int j = 0; j < 8; ++j) {
        const uint u = __float_as_uint(xs[j]);
        const uint hi = u & 0xFFFF0000u;
        const float lo = xs[j] - __uint_as_float(hi);
        h[j] = (short)(hi >> 16);
        l[j] = (short)rne_bf16(lo);
    }
}

// ---------------------------------------------------------------------------
// prep_w: WT_hi/lo[w][n][k] = split(W_w[k][n]) — transpose + hi/lo split.
// ---------------------------------------------------------------------------
__global__ __launch_bounds__(256) void prep_w(
    const float* __restrict__ Wq, const float* __restrict__ Wk,
    ushort* __restrict__ WT_hi, ushort* __restrict__ WT_lo)
{
    const int t = blockIdx.x * 256 + threadIdx.x;   // 32768 total
    const int n = t & 255;
    const int kg = ((t >> 8) & 63) * 8;
    const int w = t >> 14;
    const float* W = w ? Wk : Wq;
    float x[8];
    #pragma unroll
    for (int i = 0; i < 8; ++i) x[i] = W[(size_t)(kg + i) * 256 + n];
    uint h0, h1, h2, h3, l0, l1, l2, l3;
    h0 = pack_hi_lo(x[0], x[1], l0);
    h1 = pack_hi_lo(x[2], x[3], l1);
    h2 = pack_hi_lo(x[4], x[5], l2);
    h3 = pack_hi_lo(x[6], x[7], l3);
    const size_t off = ((size_t)w * 256 + n) * 512 + kg;
    *(uint4*)(WT_hi + off) = make_uint4(h0, h1, h2, h3);
    *(uint4*)(WT_lo + off) = make_uint4(l0, l1, l2, l3);
}

// ---------------------------------------------------------------------------
// prep_v: VT_hi/lo[b][n][k] = split(value[b][k][n]) — LDS 64x64 transpose.
// ---------------------------------------------------------------------------
__global__ __launch_bounds__(256) void prep_v(
    const float* __restrict__ value, const int* __restrict__ vlen,
    ushort* __restrict__ VT_hi, ushort* __restrict__ VT_lo)
{
    __shared__ float t[64][69];
    const int b = blockIdx.z;
    const int k0 = blockIdx.y * 64, n0 = blockIdx.x * 64;
    const int kendB = (vlen[b] + 31) & ~31;
    if (k0 >= kendB) return;

    const int tid = threadIdx.x;
    const int n_in = (tid & 15) * 4, k_in = tid >> 4;
    const float* src = value + ((size_t)b * 1024 + k0 + k_in) * 512 + n0 + n_in;
    #pragma unroll
    for (int p = 0; p < 4; ++p) {
        const float4 x = *(const float4*)(src + (size_t)p * 16 * 512);
        t[k_in + p * 16][n_in + 0] = x.x;
        t[k_in + p * 16][n_in + 1] = x.y;
        t[k_in + p * 16][n_in + 2] = x.z;
        t[k_in + p * 16][n_in + 3] = x.w;
    }
    __syncthreads();

    const int rn = tid >> 2, c0 = (tid & 3) * 16;
    uint hp[8], lp[8];
    #pragma unroll
    for (int i = 0; i < 8; ++i)
        hp[i] = pack_hi_lo(t[c0 + 2 * i][rn], t[c0 + 2 * i + 1][rn], lp[i]);
    const size_t off = ((size_t)b * 512 + n0 + rn) * 1024 + k0 + c0;
    *(uint4*)(VT_hi + off) = make_uint4(hp[0], hp[1], hp[2], hp[3]);
    *(uint4*)(VT_hi + off + 8) = make_uint4(hp[4], hp[5], hp[6], hp[7]);
    *(uint4*)(VT_lo + off) = make_uint4(lp[0], lp[1], lp[2], lp[3]);
    *(uint4*)(VT_lo + off + 8) = make_uint4(lp[4], lp[5], lp[6], lp[7]);
}

// ---------------------------------------------------------------------------
// Kernel P (MFMA): proj via 3-MFMA hi/lo bf16. A loaded f32 + in-register
// trunc-split. Wave tile 32m x 64n, K=512 by 32.
// ---------------------------------------------------------------------------
#define LOADA(s, kbase) { const int ko = (kbase) + half * 8;                   \
    _Pragma("unroll") for (int f = 0; f < 2; ++f) {                            \
        const float4 x0 = *(const float4*)(a_f + (size_t)(f * 16) * 512 + ko); \
        const float4 x1 = *(const float4*)(a_f + (size_t)(f * 16) * 512 + ko + 4); \
        split8(x0, x1, ah##s[f], al##s[f]); } }

#define LOADB(s, kbase) { const int ko = (kbase) + half * 8;                   \
    _Pragma("unroll") for (int f = 0; f < 4; ++f) {                            \
        bh##s[f] = *(const short8v*)(wt_h + (size_t)(f * 16) * 512 + ko);      \
        bl##s[f] = *(const short8v*)(wt_l + (size_t)(f * 16) * 512 + ko); } }

#define MFMAS(s)                                                                          \
    _Pragma("unroll") for (int mf = 0; mf < 2; ++mf)                                      \
    _Pragma("unroll") for (int nf = 0; nf < 4; ++nf) {                                    \
        acc[mf][nf] = __builtin_amdgcn_mfma_f32_16x16x32_bf16(ah##s[mf], bh##s[nf], acc[mf][nf], 0, 0, 0); \
        acc[mf][nf] = __builtin_amdgcn_mfma_f32_16x16x32_bf16(ah##s[mf], bl##s[nf], acc[mf][nf], 0, 0, 0); \
        acc[mf][nf] = __builtin_amdgcn_mfma_f32_16x16x32_bf16(al##s[mf], bh##s[nf], acc[mf][nf], 0, 0, 0); }

__global__ __launch_bounds__(64) void proj_mfma(
    const float* __restrict__ query, const float* __restrict__ key,
    const ushort* __restrict__ WT_hi, const ushort* __restrict__ WT_lo,
    const int* __restrict__ valid_len,
    float* __restrict__ EqT, float* __restrict__ EkT)
{
    const int lane = threadIdx.x;
    const int n0 = blockIdx.x * 64;
    const int m0 = blockIdx.y * 32;
    const bool isq = (m0 < 1024);
    int b = 0, kk0 = 0;
    if (!isq) {
        kk0 = (m0 - 1024) & 1023;
        b = (m0 - 1024) >> 10;
        if (kk0 >= valid_len[b]) return;
    }
    const int r = lane & 15, half = lane >> 4;
    const size_t wsel = isq ? 0 : (size_t)256 * 512;
    const ushort* wt_h = WT_hi + wsel + (size_t)(n0 + r) * 512;
    const ushort* wt_l = WT_lo + wsel + (size_t)(n0 + r) * 512;
    const float* a_f = isq ? (query + (size_t)(m0 + r) * 512)
                           : (key + (size_t)(m0 - 1024 + r) * 512);

    float4v acc[2][4] = {{{0.f}}};
    short8v ah0[2], al0[2], bh0[4], bl0[4];
    short8v ah1[2], al1[2], bh1[4], bl1[4];

    LOADA(0, 0); LOADB(0, 0);
    for (int kt = 0; kt < 512; kt += 64) {
        LOADA(1, kt + 32); LOADB(1, kt + 32);
        MFMAS(0);
        if (kt + 64 < 512) { LOADA(0, kt + 64); LOADB(0, kt + 64); }
        MFMAS(1);
    }

    #pragma unroll
    for (int mf = 0; mf < 2; ++mf) {
        #pragma unroll
        for (int nf = 0; nf < 4; ++nf) {
            float4v e;
            #pragma unroll
            for (int i = 0; i < 4; ++i)
                e[i] = __builtin_amdgcn_exp2f(acc[mf][nf][i] * TWO_LOG2E);
            if (isq) {
                *(float4v*)(EqT + (size_t)(n0 + nf * 16 + r) * 1024 +
                            m0 + mf * 16 + half * 4) = e;
            } else {
                *(float4v*)(EkT + (size_t)(b * 256 + n0 + nf * 16 + r) * 1024 +
                            kk0 + mf * 16 + half * 4) = e;
            }
        }
    }
}

// ---------------------------------------------------------------------------
// Score pass A (LDS-lean): P[hq][b*256+q][k] = sum_{h in quarter} wv*rcp(..).
// Thread tile 4q x 4k: per h = 1 global b128 (ek, 4 consecutive k) +
// 1 BROADCAST lds b128 (eq, wave-uniform qg) + 1 lds b32 (wv) for 16 evals —
// 4x fewer LDS-pipe cycles per eval than R9 (the ~25 us/CU LDS serialization).
// Grid 1024 = (16 qt) x (4 kt) x (4 hq) x (4 b); 256 thr = 64 kg x 4 qg.
// XCD-chunked swizzle: one (b,hq) EkT slab (256 KB) per XCD L2.
// ---------------------------------------------------------------------------
__global__ __launch_bounds__(256) void score_partial(
    const float* __restrict__ EqT, const float* __restrict__ EkT,
    const float* __restrict__ wv, const int* __restrict__ valid_len,
    float* __restrict__ P)
{
    __shared__ float eqs[64][16];   // [h-local][q]  4 KB
    __shared__ float wvs[64];

    const int orig = blockIdx.x;                     // 1024
    const int wgid = (orig & 7) * 128 + (orig >> 3); // bijective chunk-128/XCD
    const int qt = wgid & 15;
    const int kt = (wgid >> 4) & 3;
    const int hq = (wgid >> 6) & 3;
    const int b  = wgid >> 8;

    const int vlen = valid_len[b];
    if (kt * 256 >= vlen) return;                    // dead tile, fast exit

    const int tid = threadIdx.x;
    const int kg = tid & 63, qg = tid >> 6;          // wave = fixed qg
    const int k0 = kt * 256 + kg * 4;
    const int q0 = qt * 16;
    const int h0 = hq * 64;

    if (tid < 64) wvs[tid] = wv[h0 + tid];
    {
        const int i = tid * 4;
        const int h = i >> 4, q = i & 15;
        *(float4*)&eqs[h][q] =
            *(const float4*)(EqT + (size_t)(h0 + h) * 1024 + b * 256 + q0 + q);
    }
    __syncthreads();

    float acc[4][4] = {};   // [q][k]
    if (k0 < vlen) {
        const float* ekp = EkT + (size_t)(b * 256 + h0) * 1024 + k0;
        #pragma unroll 2
        for (int h = 0; h < 64; ++h) {
            const float4 ek = *(const float4*)(ekp + (size_t)h * 1024);
            const float4 eq = *(const float4*)&eqs[h][qg * 4];
            const float w = wvs[h];
            const float ekv[4] = {ek.x, ek.y, ek.z, ek.w};
            const float eqv[4] = {eq.x, eq.y, eq.z, eq.w};
            #pragma unroll
            for (int qi = 0; qi < 4; ++qi) {
                const float e = eqv[qi];
                acc[qi][0] = fmaf(w, __builtin_amdgcn_rcpf(fmaf(e, ekv[0], 1.f)), acc[qi][0]);
                acc[qi][1] = fmaf(w, __builtin_amdgcn_rcpf(fmaf(e, ekv[1], 1.f)), acc[qi][1]);
                acc[qi][2] = fmaf(w, __builtin_amdgcn_rcpf(fmaf(e, ekv[2], 1.f)), acc[qi][2]);
                acc[qi][3] = fmaf(w, __builtin_amdgcn_rcpf(fmaf(e, ekv[3], 1.f)), acc[qi][3]);
            }
        }
    }

    float* Pq = P + (size_t)hq * (1024 * 1024);
    #pragma unroll
    for (int qi = 0; qi < 4; ++qi) {
        float4 o;
        o.x = acc[qi][0]; o.y = acc[qi][1]; o.z = acc[qi][2]; o.w = acc[qi][3];
        *(float4*)(Pq + (size_t)(b * 256 + q0 + qg * 4 + qi) * 1024 + k0) = o;
    }
}

// ---------------------------------------------------------------------------
// Score pass B: masked softmax over s = -2*(P0+P1+P2+P3); bf16 hi/lo output.
// Block = (b, 4q); 1024 threads; thread owns k = tid.
// ---------------------------------------------------------------------------
__global__ __launch_bounds__(1024) void softmax_kernel(
    const float* __restrict__ P, const int* __restrict__ valid_len,
    ushort* __restrict__ attn_hi, ushort* __restrict__ attn_lo)
{
    __shared__ float red[16][4];

    const int tid = threadIdx.x;
    const int b = blockIdx.x >> 6;
    const int q0 = (blockIdx.x & 63) << 2;

    const int vlen = valid_len[b];
    const int k = tid;
    const bool v = (k < vlen);

    float s[4], m[4];
    #pragma unroll
    for (int q = 0; q < 4; ++q) {
        const size_t off = (size_t)(b * 256 + q0 + q) * 1024 + k;
        s[q] = -2.f * (P[off] + P[off + 1048576] +
                       P[off + 2097152] + P[off + 3145728]);
        m[q] = v ? s[q] : -1e30f;
    }
    #pragma unroll
    for (int o = 32; o; o >>= 1) {
        #pragma unroll
        for (int q = 0; q < 4; ++q) m[q] = fmaxf(m[q], __shfl_xor(m[q], o));
    }
    const int wid = tid >> 6;
    if ((tid & 63) == 0) {
        #pragma unroll
        for (int q = 0; q < 4; ++q) red[wid][q] = m[q];
    }
    __syncthreads();
    #pragma unroll
    for (int q = 0; q < 4; ++q) {
        float mm = red[0][q];
        #pragma unroll
        for (int w = 1; w < 16; ++w) mm = fmaxf(mm, red[w][q]);
        m[q] = mm;
    }
    __syncthreads();

    float p[4], l[4];
    #pragma unroll
    for (int q = 0; q < 4; ++q) {
        p[q] = v ? __builtin_amdgcn_exp2f((s[q] - m[q]) * LOG2E) : 0.f;
        l[q] = p[q];
    }
    #pragma unroll
    for (int o = 32; o; o >>= 1) {
        #pragma unroll
        for (int q = 0; q < 4; ++q) l[q] += __shfl_xor(l[q], o);
    }
    if ((tid & 63) == 0) {
        #pragma unroll
        for (int q = 0; q < 4; ++q) red[wid][q] = l[q];
    }
    __syncthreads();
    #pragma unroll
    for (int q = 0; q < 4; ++q) {
        float ss = red[0][q];
        #pragma unroll
        for (int w = 1; w < 16; ++w) ss += red[w][q];
        const float a = p[q] * __builtin_amdgcn_rcpf(ss);
        const uint hi = rne_bf16(a);
        const float lo = a - __uint_as_float(hi << 16);
        const size_t off = (size_t)(b * 256 + q0 + q) * 1024 + k;
        attn_hi[off] = (ushort)hi;
        attn_lo[off] = (ushort)rne_bf16(lo);
    }
}

// ---------------------------------------------------------------------------
// Kernel D (MFMA): out = attn @ value, 3-MFMA hi/lo. 4-wave blocks over one
// 32-n VT slice; XCD-chunked swizzle. grid 256 x 256 thr; wave tile 16q x 32n.
// ---------------------------------------------------------------------------
#define PVLOAD(s, ko) {                                   \
    ah##s = *(const short8v*)(ah_p + (ko));               \
    al##s = *(const short8v*)(al_p + (ko));               \
    bh0##s = *(const short8v*)(bh_p + (ko));              \
    bl0##s = *(const short8v*)(bl_p + (ko));              \
    bh1##s = *(const short8v*)(bh_p + 16 * 1024 + (ko));  \
    bl1##s = *(const short8v*)(bl_p + 16 * 1024 + (ko)); }

#define PVMFMA(s) {                                                              \
    acc0 = __builtin_amdgcn_mfma_f32_16x16x32_bf16(ah##s, bh0##s, acc0, 0, 0, 0); \
    acc0 = __builtin_amdgcn_mfma_f32_16x16x32_bf16(ah##s, bl0##s, acc0, 0, 0, 0); \
    acc0 = __builtin_amdgcn_mfma_f32_16x16x32_bf16(al##s, bh0##s, acc0, 0, 0, 0); \
    acc1 = __builtin_amdgcn_mfma_f32_16x16x32_bf16(ah##s, bh1##s, acc1, 0, 0, 0); \
    acc1 = __builtin_amdgcn_mfma_f32_16x16x32_bf16(ah##s, bl1##s, acc1, 0, 0, 0); \
    acc1 = __builtin_amdgcn_mfma_f32_16x16x32_bf16(al##s, bh1##s, acc1, 0, 0, 0); }

__global__ __launch_bounds__(256) void pv_mfma(
    const ushort* __restrict__ attn_hi, const ushort* __restrict__ attn_lo,
    const ushort* __restrict__ VT_hi, const ushort* __restrict__ VT_lo,
    const int* __restrict__ valid_len,
    float* __restrict__ out)
{
    const int orig = blockIdx.x;                 // 256
    const int wgid = (orig & 7) * 32 + (orig >> 3);
    const int qb = wgid & 3;
    const int rest = wgid >> 2;
    const int b = rest & 3;
    const int nt = rest >> 2;

    const int wid = threadIdx.x >> 6, lane = threadIdx.x & 63;
    const int n0 = nt * 32;
    const int q0 = qb * 64 + wid * 16;
    const int r = lane & 15, half = lane >> 4;
    const int kend = (valid_len[b] + 31) & ~31;

    const ushort* ah_p = attn_hi + (size_t)(b * 256 + q0 + r) * 1024 + half * 8;
    const ushort* al_p = attn_lo + (size_t)(b * 256 + q0 + r) * 1024 + half * 8;
    const ushort* bh_p = VT_hi + (size_t)(b * 512 + n0 + r) * 1024 + half * 8;
    const ushort* bl_p = VT_lo + (size_t)(b * 512 + n0 + r) * 1024 + half * 8;

    float4v acc0 = {0.f}, acc1 = {0.f};
    short8v ah0, al0, bh00, bl00, bh10, bl10;
    short8v ah1, al1, bh01, bl01, bh11, bl11;

    PVLOAD(0, 0);
    for (int kt = 0; kt < kend; kt += 64) {
        if (kt + 32 < kend) PVLOAD(1, kt + 32);
        PVMFMA(0);
        if (kt + 64 < kend) PVLOAD(0, kt + 64);
        if (kt + 32 < kend) PVMFMA(1);
    }

    float* op = out + (size_t)b * 256 * 512 + (size_t)(q0 + half * 4) * 512 + n0 + r;
    #pragma unroll
    for (int i = 0; i < 4; ++i) {
        op[(size_t)i * 512] = acc0[i];
        op[(size_t)i * 512 + 16] = acc1[i];
    }
}

// ---------------------------------------------------------------------------
extern "C" void kernel_launch(void* const* d_in, const int* in_sizes, int n_in,
                              void* d_out, int out_size, void* d_ws, size_t ws_size,
                              hipStream_t stream)
{
    const float* query = (const float*)d_in[0];   // [4,256,512]
    const float* key   = (const float*)d_in[1];   // [4,1024,512]
    const float* value = (const float*)d_in[2];   // [4,1024,512]
    const int*   vlen  = (const int*)d_in[3];     // [4]
    const float* Wq    = (const float*)d_in[4];   // [512,256]
    const float* Wk    = (const float*)d_in[5];   // [512,256]
    const float* wv    = (const float*)d_in[6];   // [256]
    float* out = (float*)d_out;                   // [4,256,512]

    float*  EqT     = (float*)d_ws;               // [256][1024]    = 262144 f
    float*  EkT     = EqT + 262144;               // [4][256][1024] = 1048576 f
    float*  P       = EkT + 1048576;              // [4][1024][1024]= 4194304 f
    ushort* WT_hi   = (ushort*)(P + 4194304);     // [2][256][512]
    ushort* WT_lo   = WT_hi + 262144;
    ushort* attn_hi = WT_lo + 262144;             // [1024][1024]
    ushort* attn_lo = attn_hi + 1048576;
    ushort* VT_hi   = attn_lo + 1048576;          // [4][512][1024]
    ushort* VT_lo   = VT_hi + 2097152;

    hipLaunchKernelGGL(prep_w, dim3(128), dim3(256), 0, stream,
                       Wq, Wk, WT_hi, WT_lo);
    hipLaunchKernelGGL(prep_v, dim3(8, 16, 4), dim3(256), 0, stream,
                       value, vlen, VT_hi, VT_lo);
    hipLaunchKernelGGL(proj_mfma, dim3(4, 160), dim3(64), 0, stream,
                       query, key, WT_hi, WT_lo, vlen, EqT, EkT);
    hipLaunchKernelGGL(score_partial, dim3(1024), dim3(256), 0, stream,
                       EqT, EkT, wv, vlen, P);
    hipLaunchKernelGGL(softmax_kernel, dim3(256), dim3(1024), 0, stream,
                       P, vlen, attn_hi, attn_lo);
    hipLaunchKernelGGL(pv_mfma, dim3(256), dim3(256), 0, stream,
                       attn_hi, attn_lo, VT_hi, VT_lo, vlen, out);
}